// Round 9
// baseline (1832.675 us; speedup 1.0000x reference)
//
#include <hip/hip_runtime.h>
#include <math.h>

#define C_ 256
#define CR_ 16
#define B_ 16
#define HW_ (128*128)
#define NCH (B_ * C_)   // 4096 channels
#define MAXPOLL 1024    // ~100 us worst-case, then compute-local fallback

typedef float f32x4 __attribute__((ext_vector_type(4)));

// ---------------- kernel A: per-channel stats (unchanged from R8) ----------
__global__ __launch_bounds__(256) void stats_kernel(const float* __restrict__ x,
                                                    float* __restrict__ mean_out,
                                                    float* __restrict__ std_out) {
    const int ch = blockIdx.x;                    // b*C + c
    const f32x4* xp = (const f32x4*)(x + (size_t)ch * HW_);
    const int t = threadIdx.x;
    float s = 0.f, ss = 0.f;
    #pragma unroll
    for (int i = 0; i < HW_ / 4 / 256; ++i) {     // 16 f32x4 per thread
        f32x4 v = xp[t + i * 256];
        s  += v.x + v.y + v.z + v.w;
        ss += v.x * v.x + v.y * v.y + v.z * v.z + v.w * v.w;
    }
    #pragma unroll
    for (int off = 32; off > 0; off >>= 1) {
        s  += __shfl_down(s, off, 64);
        ss += __shfl_down(ss, off, 64);
    }
    __shared__ float ls[4], lss[4];
    const int wid = t >> 6;
    if ((t & 63) == 0) { ls[wid] = s; lss[wid] = ss; }
    __syncthreads();
    if (t == 0) {
        float S  = ls[0] + ls[1] + ls[2] + ls[3];
        float SS = lss[0] + lss[1] + lss[2] + lss[3];
        float m = S * (1.0f / HW_);
        float v = SS * (1.0f / HW_) - m * m;
        mean_out[ch] = m;
        std_out[ch]  = sqrtf(fmaxf(v, 0.f));
    }
}

// Row-MLP: 256 threads compute mask row b into msk_sh[256].
// Inputs (mean/std) are kernel-A outputs -> plain loads are safe.
__device__ __forceinline__ void row_mlp(
    int b, int t,
    const float* __restrict__ mean_d, const float* __restrict__ std_d,
    const float* __restrict__ w1s, const float* __restrict__ b1s,
    const float* __restrict__ w2s, const float* __restrict__ b2s,
    const float* __restrict__ w1m, const float* __restrict__ b1m,
    const float* __restrict__ w2m, const float* __restrict__ b2m,
    const float* __restrict__ wb,  const float* __restrict__ bb,
    const float* __restrict__ w1f, const float* __restrict__ b1f,
    const float* __restrict__ w2f, const float* __restrict__ b2f,
    float* ds, float* dm, float* h1s, float* h1m,
    float* fsd, float* fb, float* h1f, float* msk_sh)
{
    ds[t] = std_d[b * C_ + t];
    dm[t] = mean_d[b * C_ + t];
    __syncthreads();

    if (t < 32) {
        const int r = t & 15;
        const bool is_std = (t < 16);
        const float* wgt = is_std ? w1s : w1m;
        const float* src = is_std ? ds : dm;
        float acc = is_std ? b1s[r] : b1m[r];
        for (int c = 0; c < C_; ++c) acc += src[c] * wgt[r * C_ + c];
        acc = fmaxf(acc, 0.f);
        if (is_std) h1s[r] = acc; else h1m[r] = acc;
    }
    __syncthreads();

    {
        float accs = b2s[t], accm = b2m[t];
        #pragma unroll
        for (int r = 0; r < CR_; ++r) {
            accs += h1s[r] * w2s[t * CR_ + r];
            accm += h1m[r] * w2m[t * CR_ + r];
        }
        fsd[t]      = accs;
        fsd[C_ + t] = accm;
    }
    __syncthreads();

    {
        float acc = bb[t];
        const f32x4* wr = (const f32x4*)(wb + (size_t)t * 2 * C_);
        #pragma unroll 4
        for (int j = 0; j < 2 * C_ / 4; ++j) {
            f32x4 w4 = wr[j];
            acc += fsd[4 * j]     * w4.x + fsd[4 * j + 1] * w4.y
                 + fsd[4 * j + 2] * w4.z + fsd[4 * j + 3] * w4.w;
        }
        fb[t] = fmaxf(acc, 0.f);
    }
    __syncthreads();

    if (t < CR_) {
        float acc = b1f[t];
        for (int c = 0; c < C_; ++c) acc += fb[c] * w1f[t * C_ + c];
        h1f[t] = fmaxf(acc, 0.f);
    }
    __syncthreads();

    {
        float acc = b2f[t];
        #pragma unroll
        for (int r = 0; r < CR_; ++r) acc += h1f[r] * w2f[t * CR_ + r];
        msk_sh[t] = 1.0f / (1.0f + expf(-acc));
    }
    __syncthreads();
}

// ---------------- kernel B: mlp (owner-per-row) + scale --------------------
__global__ __launch_bounds__(256) void mlp_scale_kernel(
    const float* __restrict__ x,
    const float* __restrict__ mean_d, const float* __restrict__ std_d,
    const float* __restrict__ w1s, const float* __restrict__ b1s,
    const float* __restrict__ w2s, const float* __restrict__ b2s,
    const float* __restrict__ w1m, const float* __restrict__ b1m,
    const float* __restrict__ w2m, const float* __restrict__ b2m,
    const float* __restrict__ wb,  const float* __restrict__ bb,
    const float* __restrict__ w1f, const float* __restrict__ b1f,
    const float* __restrict__ w2f, const float* __restrict__ b2f,
    float* mask_ws, unsigned* go_flags,
    float* __restrict__ out)
{
    const int ch = blockIdx.x;        // b*C + c
    const int t  = threadIdx.x;
    const int b  = ch >> 8;
    const int c  = ch & (C_ - 1);
    unsigned* goflag = &go_flags[b * 16];   // one cache line per row

    __shared__ float ds[C_], dm[C_];
    __shared__ float h1s[CR_], h1m[CR_];
    __shared__ float fsd[2 * C_];
    __shared__ float fb[C_];
    __shared__ float h1f[CR_];
    __shared__ float msk_sh[C_];
    __shared__ int   state;           // 0 poll, 1 flag-ready, 2 timeout

    float m;
    if (c == 0) {
        // owner: compute row mask, publish, release flag
        row_mlp(b, t, mean_d, std_d, w1s, b1s, w2s, b2s, w1m, b1m, w2m, b2m,
                wb, bb, w1f, b1f, w2f, b2f,
                ds, dm, h1s, h1m, fsd, fb, h1f, msk_sh);
        __hip_atomic_store(&mask_ws[b * C_ + t], msk_sh[t],
                           __ATOMIC_RELAXED, __HIP_MEMORY_SCOPE_AGENT);
        __syncthreads();              // drains stores before the flag
        if (t == 0)
            __hip_atomic_store(goflag, 1u, __ATOMIC_RELEASE,
                               __HIP_MEMORY_SCOPE_AGENT);
        m = msk_sh[0];
    } else {
        // non-owner: read-only acquire poll with bounded timeout
        if (t == 0) state = 0;
        __syncthreads();
        for (int it = 0; it < MAXPOLL; ++it) {
            if (t == 0) {
                if (__hip_atomic_load(goflag, __ATOMIC_ACQUIRE,
                                      __HIP_MEMORY_SCOPE_AGENT) != 0u)
                    state = 1;
                else if (it == MAXPOLL - 1)
                    state = 2;
            }
            __syncthreads();
            if (state != 0) break;
            __builtin_amdgcn_s_sleep(2);
            __syncthreads();
        }
        if (state == 1) {
            m = __hip_atomic_load(&mask_ws[ch], __ATOMIC_RELAXED,
                                  __HIP_MEMORY_SCOPE_AGENT);
        } else {
            // fallback: compute row MLP locally (deadlock-free by construction)
            row_mlp(b, t, mean_d, std_d, w1s, b1s, w2s, b2s, w1m, b1m, w2m, b2m,
                    wb, bb, w1f, b1f, w2f, b2f,
                    ds, dm, h1s, h1m, fsd, fb, h1f, msk_sh);
            m = msk_sh[c];
        }
    }

    // ---- scale: 16 x {load f32x4, mul, nt-store} over 64 KiB channel ----
    const f32x4* xp = (const f32x4*)(x + (size_t)ch * HW_);
    f32x4* op = (f32x4*)(out + (size_t)ch * HW_);
    #pragma unroll
    for (int i = 0; i < HW_ / 4 / 256; ++i) {
        f32x4 v = xp[t + i * 256];
        v.x *= m; v.y *= m; v.z *= m; v.w *= m;
        __builtin_nontemporal_store(v, op + t + i * 256);
    }
}

extern "C" void kernel_launch(void* const* d_in, const int* in_sizes, int n_in,
                              void* d_out, int out_size, void* d_ws, size_t ws_size,
                              hipStream_t stream) {
    const float* x   = (const float*)d_in[0];
    const float* w1s = (const float*)d_in[1];
    const float* b1s = (const float*)d_in[2];
    const float* w2s = (const float*)d_in[3];
    const float* b2s = (const float*)d_in[4];
    const float* w1m = (const float*)d_in[5];
    const float* b1m = (const float*)d_in[6];
    const float* w2m = (const float*)d_in[7];
    const float* b2m = (const float*)d_in[8];
    const float* wb  = (const float*)d_in[9];
    const float* bb  = (const float*)d_in[10];
    const float* w1f = (const float*)d_in[11];
    const float* b1f = (const float*)d_in[12];
    const float* w2f = (const float*)d_in[13];
    const float* b2f = (const float*)d_in[14];
    float* out = (float*)d_out;

    float*    mean_ws  = (float*)d_ws;                   // B*C floats
    float*    std_ws   = mean_ws + NCH;                  // B*C floats
    float*    mask_ws  = std_ws + NCH;                   // B*C floats
    unsigned* go_flags = (unsigned*)(mask_ws + NCH);     // 16 rows x 16 u32 (64B apart)

    hipMemsetAsync((void*)go_flags, 0, B_ * 16 * sizeof(unsigned), stream);

    stats_kernel<<<NCH, 256, 0, stream>>>(x, mean_ws, std_ws);
    mlp_scale_kernel<<<NCH, 256, 0, stream>>>(x, mean_ws, std_ws,
        w1s, b1s, w2s, b2s, w1m, b1m, w2m, b2m,
        wb, bb, w1f, b1f, w2f, b2f,
        mask_ws, go_flags, out);
}

// Round 10
// 155.399 us; speedup vs baseline: 11.7933x; 11.7933x over previous
//
#include <hip/hip_runtime.h>
#include <math.h>

#define C_ 256
#define CR_ 16
#define B_ 16
#define HW_ (128*128)
#define NCH (B_ * C_)   // 4096 channels

typedef float f32x4 __attribute__((ext_vector_type(4)));

__global__ __launch_bounds__(256) void stats_kernel(const float* __restrict__ x,
                                                    float* __restrict__ mean_out,
                                                    float* __restrict__ std_out) {
    const int ch = blockIdx.x;                    // b*C + c
    const f32x4* xp = (const f32x4*)(x + (size_t)ch * HW_);
    const int t = threadIdx.x;
    float s = 0.f, ss = 0.f;
    #pragma unroll
    for (int i = 0; i < HW_ / 4 / 256; ++i) {     // 16 f32x4 per thread
        f32x4 v = xp[t + i * 256];
        s  += v.x + v.y + v.z + v.w;
        ss += v.x * v.x + v.y * v.y + v.z * v.z + v.w * v.w;
    }
    #pragma unroll
    for (int off = 32; off > 0; off >>= 1) {
        s  += __shfl_down(s, off, 64);
        ss += __shfl_down(ss, off, 64);
    }
    __shared__ float ls[4], lss[4];
    const int wid = t >> 6;
    if ((t & 63) == 0) { ls[wid] = s; lss[wid] = ss; }
    __syncthreads();
    if (t == 0) {
        float S  = ls[0] + ls[1] + ls[2] + ls[3];
        float SS = lss[0] + lss[1] + lss[2] + lss[3];
        float m = S * (1.0f / HW_);
        float v = SS * (1.0f / HW_) - m * m;
        mean_out[ch] = m;
        std_out[ch]  = sqrtf(fmaxf(v, 0.f));
    }
}

__global__ __launch_bounds__(256) void mlp_kernel(
    const float* __restrict__ mean_d, const float* __restrict__ std_d,
    const float* __restrict__ w1s, const float* __restrict__ b1s,
    const float* __restrict__ w2s, const float* __restrict__ b2s,
    const float* __restrict__ w1m, const float* __restrict__ b1m,
    const float* __restrict__ w2m, const float* __restrict__ b2m,
    const float* __restrict__ wb,  const float* __restrict__ bb,
    const float* __restrict__ w1f, const float* __restrict__ b1f,
    const float* __restrict__ w2f, const float* __restrict__ b2f,
    float* __restrict__ mask_out)
{
    const int b = blockIdx.x;
    const int t = threadIdx.x;
    __shared__ float ds[C_], dm[C_];
    __shared__ float h1s[CR_], h1m[CR_];
    __shared__ float fused[2 * C_];
    __shared__ float fb[C_];
    __shared__ float h1f[CR_];

    ds[t] = std_d[b * C_ + t];
    dm[t] = mean_d[b * C_ + t];
    __syncthreads();

    // SE first layers: threads 0..15 -> std branch, 16..31 -> mean branch
    if (t < 32) {
        const int r = t & 15;
        const bool is_std = (t < 16);
        const float* w   = is_std ? w1s : w1m;
        const float* src = is_std ? ds : dm;
        float acc = is_std ? b1s[r] : b1m[r];
        for (int c = 0; c < C_; ++c) acc += src[c] * w[r * C_ + c];
        acc = fmaxf(acc, 0.f);
        if (is_std) h1s[r] = acc; else h1m[r] = acc;
    }
    __syncthreads();

    // SE second layers: thread t -> fused[t] (std), fused[C+t] (mean)
    {
        float accs = b2s[t], accm = b2m[t];
        #pragma unroll
        for (int r = 0; r < CR_; ++r) {
            accs += h1s[r] * w2s[t * CR_ + r];
            accm += h1m[r] * w2m[t * CR_ + r];
        }
        fused[t]      = accs;
        fused[C_ + t] = accm;
    }
    __syncthreads();

    // bottleneck: fb[t] = relu(dot(fused, wb[t,:]) + bb[t])
    {
        float acc = bb[t];
        const f32x4* wr = (const f32x4*)(wb + (size_t)t * 2 * C_);
        #pragma unroll 4
        for (int j = 0; j < 2 * C_ / 4; ++j) {
            f32x4 w4 = wr[j];
            acc += fused[4 * j]     * w4.x + fused[4 * j + 1] * w4.y
                 + fused[4 * j + 2] * w4.z + fused[4 * j + 3] * w4.w;
        }
        fb[t] = fmaxf(acc, 0.f);
    }
    __syncthreads();

    // final SE layer 1
    if (t < 16) {
        float acc = b1f[t];
        for (int c = 0; c < C_; ++c) acc += fb[c] * w1f[t * C_ + c];
        h1f[t] = fmaxf(acc, 0.f);
    }
    __syncthreads();

    // final SE layer 2 + sigmoid
    {
        float acc = b2f[t];
        #pragma unroll
        for (int r = 0; r < CR_; ++r) acc += h1f[r] * w2f[t * CR_ + r];
        mask_out[b * C_ + t] = 1.0f / (1.0f + expf(-acc));
    }
}

// Scale: one channel per block; mask hoisted to one block-uniform load.
// Two-phase: all 16 f32x4 loads issued into registers (read burst),
// then 16 nt-stores (write burst) -- minimizes read/write turnaround.
__global__ __launch_bounds__(256) void scale_kernel(const float* __restrict__ x,
                                                    const float* __restrict__ mask,
                                                    float* __restrict__ out) {
    const int ch = blockIdx.x;
    const int t  = threadIdx.x;
    const float m = mask[ch];
    const f32x4* xp = (const f32x4*)(x + (size_t)ch * HW_);
    f32x4* op = (f32x4*)(out + (size_t)ch * HW_);

    f32x4 v[16];
    #pragma unroll
    for (int i = 0; i < 16; ++i)
        v[i] = xp[t + i * 256];
    #pragma unroll
    for (int i = 0; i < 16; ++i) {
        f32x4 r = v[i];
        r.x *= m; r.y *= m; r.z *= m; r.w *= m;
        __builtin_nontemporal_store(r, op + t + i * 256);
    }
}

extern "C" void kernel_launch(void* const* d_in, const int* in_sizes, int n_in,
                              void* d_out, int out_size, void* d_ws, size_t ws_size,
                              hipStream_t stream) {
    const float* x   = (const float*)d_in[0];
    const float* w1s = (const float*)d_in[1];
    const float* b1s = (const float*)d_in[2];
    const float* w2s = (const float*)d_in[3];
    const float* b2s = (const float*)d_in[4];
    const float* w1m = (const float*)d_in[5];
    const float* b1m = (const float*)d_in[6];
    const float* w2m = (const float*)d_in[7];
    const float* b2m = (const float*)d_in[8];
    const float* wb  = (const float*)d_in[9];
    const float* bb  = (const float*)d_in[10];
    const float* w1f = (const float*)d_in[11];
    const float* b1f = (const float*)d_in[12];
    const float* w2f = (const float*)d_in[13];
    const float* b2f = (const float*)d_in[14];
    float* out = (float*)d_out;

    float* mean_ws = (float*)d_ws;                 // B*C floats
    float* std_ws  = mean_ws + NCH;                // B*C floats
    float* mask_ws = std_ws + NCH;                 // B*C floats

    stats_kernel<<<NCH, 256, 0, stream>>>(x, mean_ws, std_ws);
    mlp_kernel<<<B_, 256, 0, stream>>>(mean_ws, std_ws,
                                       w1s, b1s, w2s, b2s,
                                       w1m, b1m, w2m, b2m,
                                       wb, bb, w1f, b1f, w2f, b2f,
                                       mask_ws);
    scale_kernel<<<NCH, 256, 0, stream>>>(x, mask_ws, out);
}